// Round 2
// baseline (1007.497 us; speedup 1.0000x reference)
//
#include <hip/hip_runtime.h>

// ---------- types ----------
typedef __bf16 bf16_t;
typedef bf16_t bf16x8 __attribute__((ext_vector_type(8)));
typedef float f32x4 __attribute__((ext_vector_type(4)));

__device__ inline f32x4 mfma16(bf16x8 a, bf16x8 b, f32x4 c) {
    return __builtin_amdgcn_mfma_f32_16x16x32_bf16(a, b, c, 0, 0, 0);
}

__device__ inline ushort f2bf(float f) {
    unsigned u = __builtin_bit_cast(unsigned, f);
    unsigned r = (u + 0x7FFFu + ((u >> 16) & 1u)) >> 16;
    return (ushort)r;
}

__device__ inline void gload_lds16(const void* g, void* l) {
    __builtin_amdgcn_global_load_lds(
        (const __attribute__((address_space(1))) void*)g,
        (__attribute__((address_space(3))) void*)l, 16, 0, 0);
}

// ---------- problem constants ----------
// B=16, Ktok=1024, D=512, HS=2048, HR=1024, E=8
// M = 16384, units: 0,1 = shared halves (scale 1), 2..9 = experts (scale rw[b,e])
#define M_TOT 16384
#define D_DIM 512
#define H_UNIT 1024
#define N_UNITS 10
#define UNIT_W_ELEMS (1024*512)

// ---------- conversion kernels ----------
__global__ void k_cvt_x(const float* __restrict__ x, ushort* __restrict__ xb) {
    int i = (blockIdx.x * 256 + threadIdx.x) * 4;
    float4 v = *reinterpret_cast<const float4*>(x + i);
    ushort4 o;
    o.x = f2bf(v.x); o.y = f2bf(v.y); o.z = f2bf(v.z); o.w = f2bf(v.w);
    *reinterpret_cast<ushort4*>(xb + i) = o;
}

// transpose [ROWS x COLS] f32 submatrix (per unit) -> [COLS x ROWS] bf16
// MODE 0: gate/up.  shared: Wsh is [512][2048], unit u<2 takes col block u*1024; routed Wrt [e][512][1024]
// MODE 1: down.     shared: Wsh is [2048][512], unit u<2 takes row block u*1024; routed Wrt [e][1024][512]
template<int ROWS, int COLS, int MODE>
__global__ void k_trans(const float* __restrict__ Wsh, const float* __restrict__ Wrt,
                        ushort* __restrict__ dst) {
    int u = blockIdx.z;
    const float* src; int stride;
    if (MODE == 0) {
        if (u < 2) { src = Wsh + u * COLS; stride = 2 * COLS; }
        else       { src = Wrt + (size_t)(u - 2) * ROWS * COLS; stride = COLS; }
    } else {
        src = (u < 2) ? (Wsh + (size_t)u * ROWS * COLS)
                      : (Wrt + (size_t)(u - 2) * ROWS * COLS);
        stride = COLS;
    }
    __shared__ float t[64][65];
    int r0 = blockIdx.y * 64, c0 = blockIdx.x * 64;
    int tid = threadIdx.x;
#pragma unroll
    for (int i = 0; i < 16; ++i) {
        int idx = i * 256 + tid;
        int r = idx >> 6, c = idx & 63;
        t[r][c] = src[(r0 + r) * stride + c0 + c];
    }
    __syncthreads();
    ushort* d = dst + (size_t)u * ROWS * COLS;
#pragma unroll
    for (int i = 0; i < 16; ++i) {
        int idx = i * 256 + tid;
        int r = idx >> 6, c = idx & 63;
        d[(c0 + r) * ROWS + (r0 + c)] = f2bf(t[c][r]);
    }
}

// out[m][d] = bs_down[d] + sum_e rw[b][e]*br_down[e][d]
__global__ void k_init_out(const float* __restrict__ bsd, const float* __restrict__ brd,
                           const float* __restrict__ rw, float* __restrict__ out) {
    int i = (blockIdx.x * 256 + threadIdx.x) * 4;
    int d = i & 511;
    int m = i >> 9;
    int b = m >> 10;
    float4 v = *reinterpret_cast<const float4*>(bsd + d);
#pragma unroll
    for (int e = 0; e < 8; ++e) {
        float w = rw[b * 8 + e];
        float4 bb = *reinterpret_cast<const float4*>(brd + e * 512 + d);
        v.x += w * bb.x; v.y += w * bb.y; v.z += w * bb.z; v.w += w * bb.w;
    }
    *reinterpret_cast<float4*>(out + i) = v;
}

// ---------- GEMM 1: fused gate+up+SwiGLU ----------
// A [M][512] bf16, Bg/Bu [1024][512] bf16 (N-major), H out [M][1024] bf16
// 128x128 tile, BK=32, 256 thr = 4 waves (2x2), wave tile 64x64, dual acc.
__global__ __launch_bounds__(256, 2) void gemm_gateup(
    const ushort* __restrict__ A, const ushort* __restrict__ Bg, const ushort* __restrict__ Bu,
    const float* __restrict__ bg, const float* __restrict__ bu,
    const float* __restrict__ rw, ushort* __restrict__ H, int e_idx) {
    constexpr int K = 512, N = 1024;
    __shared__ ushort lsA[128 * 32];
    __shared__ ushort lsG[128 * 32];
    __shared__ ushort lsU[128 * 32];
    const int tid = threadIdx.x;
    const int l = tid & 63, w = tid >> 6;
    const int wm = w >> 1, wn = w & 1;
    const int bm = blockIdx.y * 128, bn = blockIdx.x * 128;

    f32x4 accg[4][4] = {};
    f32x4 accu[4][4] = {};

    for (int kk = 0; kk < K; kk += 32) {
#pragma unroll
        for (int j = 0; j < 2; ++j) {
            int q = w * 2 + j;         // 1KB block id 0..7
            int c = q * 64 + l;        // 16B chunk 0..511
            int row = c >> 2, cw = c & 3;
            int ga = (bm + row) * K + kk + cw * 8;
            int gb = (bn + row) * K + kk + cw * 8;
            gload_lds16(A + ga, lsA + q * 512);
            gload_lds16(Bg + gb, lsG + q * 512);
            gload_lds16(Bu + gb, lsU + q * 512);
        }
        __syncthreads();
        bf16x8 af[4], gf[4], uf[4];
#pragma unroll
        for (int i = 0; i < 4; ++i) {
            int ar = wm * 64 + i * 16 + (l & 15);
            int br = wn * 64 + i * 16 + (l & 15);
            af[i] = *reinterpret_cast<const bf16x8*>(&lsA[ar * 32 + (l >> 4) * 8]);
            gf[i] = *reinterpret_cast<const bf16x8*>(&lsG[br * 32 + (l >> 4) * 8]);
            uf[i] = *reinterpret_cast<const bf16x8*>(&lsU[br * 32 + (l >> 4) * 8]);
        }
#pragma unroll
        for (int mi = 0; mi < 4; ++mi)
#pragma unroll
            for (int ni = 0; ni < 4; ++ni) {
                accg[mi][ni] = mfma16(af[mi], gf[ni], accg[mi][ni]);
                accu[mi][ni] = mfma16(af[mi], uf[ni], accu[mi][ni]);
            }
        __syncthreads();
    }

    const float scale = (e_idx < 0) ? 1.0f : rw[(bm >> 10) * 8 + e_idx];
#pragma unroll
    for (int ni = 0; ni < 4; ++ni) {
        int col = bn + wn * 64 + ni * 16 + (l & 15);
        float bgv = bg[col], buv = bu[col];
#pragma unroll
        for (int mi = 0; mi < 4; ++mi)
#pragma unroll
            for (int r = 0; r < 4; ++r) {
                int row = bm + wm * 64 + mi * 16 + (l >> 4) * 4 + r;
                float g = accg[mi][ni][r] + bgv;
                float u = accu[mi][ni][r] + buv;
                float h = g / (1.0f + __expf(-g)) * u * scale;
                H[row * N + col] = f2bf(h);
            }
    }
}

// ---------- GEMM 2: down, accumulate into out ----------
// A = H [M][1024] bf16, Bt [512][1024] bf16 (N-major), out [M][512] f32 +=
__global__ __launch_bounds__(256, 2) void gemm_down(
    const ushort* __restrict__ A, const ushort* __restrict__ Bt,
    float* __restrict__ out) {
    constexpr int K = 1024, N = 512;
    __shared__ ushort lsA[128 * 32];
    __shared__ ushort lsB[128 * 32];
    const int tid = threadIdx.x;
    const int l = tid & 63, w = tid >> 6;
    const int wm = w >> 1, wn = w & 1;
    const int bm = blockIdx.y * 128, bn = blockIdx.x * 128;

    f32x4 acc[4][4] = {};

    for (int kk = 0; kk < K; kk += 32) {
#pragma unroll
        for (int j = 0; j < 2; ++j) {
            int q = w * 2 + j;
            int c = q * 64 + l;
            int row = c >> 2, cw = c & 3;
            int ga = (bm + row) * K + kk + cw * 8;
            int gb = (bn + row) * K + kk + cw * 8;
            gload_lds16(A + ga, lsA + q * 512);
            gload_lds16(Bt + gb, lsB + q * 512);
        }
        __syncthreads();
        bf16x8 af[4], bf[4];
#pragma unroll
        for (int i = 0; i < 4; ++i) {
            int ar = wm * 64 + i * 16 + (l & 15);
            int br = wn * 64 + i * 16 + (l & 15);
            af[i] = *reinterpret_cast<const bf16x8*>(&lsA[ar * 32 + (l >> 4) * 8]);
            bf[i] = *reinterpret_cast<const bf16x8*>(&lsB[br * 32 + (l >> 4) * 8]);
        }
#pragma unroll
        for (int mi = 0; mi < 4; ++mi)
#pragma unroll
            for (int ni = 0; ni < 4; ++ni)
                acc[mi][ni] = mfma16(af[mi], bf[ni], acc[mi][ni]);
        __syncthreads();
    }

#pragma unroll
    for (int ni = 0; ni < 4; ++ni) {
        int col = bn + wn * 64 + ni * 16 + (l & 15);
#pragma unroll
        for (int mi = 0; mi < 4; ++mi)
#pragma unroll
            for (int r = 0; r < 4; ++r) {
                int row = bm + wm * 64 + mi * 16 + (l >> 4) * 4 + r;
                out[row * N + col] += acc[mi][ni][r];
            }
    }
}

// ---------- launch ----------
extern "C" void kernel_launch(void* const* d_in, const int* in_sizes, int n_in,
                              void* d_out, int out_size, void* d_ws, size_t ws_size,
                              hipStream_t stream) {
    const float* x   = (const float*)d_in[0];
    const float* rw  = (const float*)d_in[1];
    const float* Wsg = (const float*)d_in[2];
    const float* bsg = (const float*)d_in[3];
    const float* Wsu = (const float*)d_in[4];
    const float* bsu = (const float*)d_in[5];
    const float* Wsd = (const float*)d_in[6];
    const float* bsd = (const float*)d_in[7];
    const float* Wrg = (const float*)d_in[8];
    const float* brg = (const float*)d_in[9];
    const float* Wru = (const float*)d_in[10];
    const float* bru = (const float*)d_in[11];
    const float* Wrd = (const float*)d_in[12];
    const float* brd = (const float*)d_in[13];
    float* out = (float*)d_out;

    char* ws = (char*)d_ws;
    ushort* xb  = (ushort*)ws; ws += (size_t)M_TOT * D_DIM * 2;        // 16.8 MB
    ushort* wgT = (ushort*)ws; ws += (size_t)N_UNITS * UNIT_W_ELEMS * 2; // 10.5 MB
    ushort* wuT = (ushort*)ws; ws += (size_t)N_UNITS * UNIT_W_ELEMS * 2;
    ushort* wdT = (ushort*)ws; ws += (size_t)N_UNITS * UNIT_W_ELEMS * 2;
    ushort* Hb  = (ushort*)ws; ws += (size_t)M_TOT * H_UNIT * 2;       // 33.5 MB

    k_cvt_x<<<8192, 256, 0, stream>>>(x, xb);
    k_trans<512, 1024, 0><<<dim3(16, 8, 10), 256, 0, stream>>>(Wsg, Wrg, wgT);
    k_trans<512, 1024, 0><<<dim3(16, 8, 10), 256, 0, stream>>>(Wsu, Wru, wuT);
    k_trans<1024, 512, 1><<<dim3(8, 16, 10), 256, 0, stream>>>(Wsd, Wrd, wdT);
    k_init_out<<<8192, 256, 0, stream>>>(bsd, brd, rw, out);

    for (int u = 0; u < N_UNITS; ++u) {
        const ushort* wg = wgT + (size_t)u * UNIT_W_ELEMS;
        const ushort* wu = wuT + (size_t)u * UNIT_W_ELEMS;
        const ushort* wd = wdT + (size_t)u * UNIT_W_ELEMS;
        const float* bgB = (u < 2) ? (bsg + u * 1024) : (brg + (u - 2) * 1024);
        const float* buB = (u < 2) ? (bsu + u * 1024) : (bru + (u - 2) * 1024);
        int e_idx = (u < 2) ? -1 : (u - 2);
        gemm_gateup<<<dim3(8, 128), 256, 0, stream>>>(xb, wg, wu, bgB, buB, rw, Hb, e_idx);
        gemm_down<<<dim3(4, 128), 256, 0, stream>>>(Hb, wd, out);
    }
}